// Round 3
// baseline (343.959 us; speedup 1.0000x reference)
//
#include <hip/hip_runtime.h>
#include <math.h>

// QuadraticNetCholesky via MFMA.
// Per wave: 128 samples in 4 groups of 32 (2 sample-tiles of 16).
// L1: D=W1·X^T (3-term bf16 hi/lo, bias folded at k=12), L2: D=W2·H1^T,
// L3: D=W3·H2^T (single bf16). All with v_mfma_f32_16x16x32_bf16:
//   A[m=lane&15][k=quad*8+j], B[k=quad*8+j][n=lane&15],
//   D col=lane&15, row=quad*4+reg  (layouts HW-verified per guide m89/m91/m120).
// Weights live in VGPR fragments (no per-sample weight traffic).
// L·L^T on VALU (lane-per-sample), output through row-batch LDS staging:
// 192 B (3-cache-line) aligned runs -> zero write amplification.

typedef __attribute__((ext_vector_type(8))) short bf16x8;
typedef __attribute__((ext_vector_type(4))) short bf16x4;
typedef __attribute__((ext_vector_type(4))) float f32x4;

#define MFMA(a, b, c) __builtin_amdgcn_mfma_f32_16x16x32_bf16((a), (b), (c), 0, 0, 0)

namespace {

constexpr int WREG = 16384;   // per-wave LDS region (4 waves -> 64 KB exactly)
constexpr int oL   = 0;       // L [32][84] f32 (336 B rows) | staging [32][52] f32 (208 B rows)
constexpr int oX   = 10752;   // X [16][20] f32 (80 B rows)  | H2 [16][40] bf16 (80 B rows)
constexpr int oH1  = 12032;   // H1 [16][136] bf16 (272 B rows)

__device__ __forceinline__ unsigned short rne_bf16(float f) {
    unsigned u = __float_as_uint(f);
    u += 0x7fffu + ((u >> 16) & 1u);
    return (unsigned short)(u >> 16);
}
__device__ __forceinline__ float bf16f(unsigned short h) {
    return __uint_as_float(((unsigned)h) << 16);
}
__device__ __forceinline__ float elu_f(float v)      { return v > 0.f ? v : __expf(v) - 1.f; }
__device__ __forceinline__ float softplus_f(float v) { return fmaxf(v, 0.f) + __logf(1.f + __expf(-fabsf(v))); }

__global__ __launch_bounds__(256, 2) void qnc_mfma(
    const float* __restrict__ x,
    const float* __restrict__ W1, const float* __restrict__ b1,
    const float* __restrict__ W2, const float* __restrict__ b2,
    const float* __restrict__ W3, const float* __restrict__ b3,
    float* __restrict__ out)
{
    __shared__ __align__(16) char smem[4 * WREG];
    const int t    = threadIdx.x;
    const int wv   = t >> 6;
    const int lane = t & 63;
    const int quad = lane >> 4;
    const int l16  = lane & 15;
    char* wb = smem + wv * WREG;

    // ---------------- one-time: weight fragments into VGPRs ----------------
    // W1 A-frags (hi+lo), K=32 padded: k=0..11 = W1 row, k=12 = b1, k>12 = 0.
    bf16x8 w1hi[8], w1lo[8];
    #pragma unroll
    for (int mt = 0; mt < 8; ++mt) {
        const int feat = mt * 16 + l16;
        float v[8];
        if (quad == 0) {
            const float4 a = *(const float4*)(W1 + feat * 12);
            const float4 b = *(const float4*)(W1 + feat * 12 + 4);
            v[0]=a.x; v[1]=a.y; v[2]=a.z; v[3]=a.w; v[4]=b.x; v[5]=b.y; v[6]=b.z; v[7]=b.w;
        } else if (quad == 1) {
            const float4 a = *(const float4*)(W1 + feat * 12 + 8);
            v[0]=a.x; v[1]=a.y; v[2]=a.z; v[3]=b1[feat]; v[4]=0.f; v[5]=0.f; v[6]=0.f; v[7]=0.f;
            // k = 8+j: j=0..3 -> cols 8..11; j=4 -> k=12 -> bias ... fix below
        } else {
            #pragma unroll
            for (int j = 0; j < 8; ++j) v[j] = 0.f;
        }
        // correct quad==1 mapping: k=8+j -> j=0..3 are cols 8..11, j=4 is k=12 (bias)
        if (quad == 1) { v[4] = v[3]; v[3] = 0.f; }           // shift: v[3] was b1
        if (quad == 1) { const float4 a = *(const float4*)(W1 + feat * 12 + 8);
                         v[0]=a.x; v[1]=a.y; v[2]=a.z; v[3]=a.w; }
        bf16x8 h, l;
        #pragma unroll
        for (int j = 0; j < 8; ++j) {
            const unsigned short hb = rne_bf16(v[j]);
            h[j] = (short)hb;
            l[j] = (short)rne_bf16(v[j] - bf16f(hb));
        }
        w1hi[mt] = h; w1lo[mt] = l;
    }
    // W2 A-frags (single bf16): feat = 16mt+l16, k = 32kt + quad*8 + j
    bf16x8 w2f[2][4];
    #pragma unroll
    for (int mt = 0; mt < 2; ++mt) {
        const int feat = mt * 16 + l16;
        #pragma unroll
        for (int kt = 0; kt < 4; ++kt) {
            const float* p = W2 + feat * 128 + kt * 32 + quad * 8;
            const float4 a = *(const float4*)p;
            const float4 b = *(const float4*)(p + 4);
            bf16x8 h;
            h[0]=(short)rne_bf16(a.x); h[1]=(short)rne_bf16(a.y);
            h[2]=(short)rne_bf16(a.z); h[3]=(short)rne_bf16(a.w);
            h[4]=(short)rne_bf16(b.x); h[5]=(short)rne_bf16(b.y);
            h[6]=(short)rne_bf16(b.z); h[7]=(short)rne_bf16(b.w);
            w2f[mt][kt] = h;
        }
    }
    // W3 A-frags: feat = 16mt+l16 (80-pad rows >=78 are zero), k = quad*8+j
    bf16x8 w3f[5];
    #pragma unroll
    for (int mt = 0; mt < 5; ++mt) {
        const int feat = mt * 16 + l16;
        bf16x8 h = (bf16x8){0,0,0,0,0,0,0,0};
        if (feat < 78) {
            const float* p = W3 + feat * 32 + quad * 8;
            const float4 a = *(const float4*)p;
            const float4 b = *(const float4*)(p + 4);
            h[0]=(short)rne_bf16(a.x); h[1]=(short)rne_bf16(a.y);
            h[2]=(short)rne_bf16(a.z); h[3]=(short)rne_bf16(a.w);
            h[4]=(short)rne_bf16(b.x); h[5]=(short)rne_bf16(b.y);
            h[6]=(short)rne_bf16(b.z); h[7]=(short)rne_bf16(b.w);
        }
        w3f[mt] = h;
    }
    // biases for D rows (feat = 16mt + 4*quad + r)
    float b2r[2][4], b3r[5][4];
    #pragma unroll
    for (int mt = 0; mt < 2; ++mt)
        #pragma unroll
        for (int r = 0; r < 4; ++r) b2r[mt][r] = b2[mt * 16 + quad * 4 + r];
    #pragma unroll
    for (int mt = 0; mt < 5; ++mt)
        #pragma unroll
        for (int r = 0; r < 4; ++r) {
            const int f3 = mt * 16 + quad * 4 + r;
            b3r[mt][r] = (f3 < 78) ? b3[f3] : 0.f;
        }

    const long gwbase = ((long)blockIdx.x * 4 + wv) * 128;

    #pragma unroll 1
    for (int g = 0; g < 4; ++g) {
        const long base32 = gwbase + (long)g * 32;

        #pragma unroll 1
        for (int nt = 0; nt < 2; ++nt) {
            const long base16 = base32 + nt * 16;
            // ---- stage X [16][20] f32: cols 0-11 data, col 12 = 1.0, 13-15 = 0 ----
            if (lane < 48) {
                const int samp = lane / 3, q = lane - samp * 3;
                const float4 vx = *(const float4*)(x + (size_t)(base16 + samp) * 12 + q * 4);
                *(float4*)(wb + oX + samp * 80 + q * 16) = vx;
            }
            if (lane < 16)
                *(float4*)(wb + oX + lane * 80 + 48) = make_float4(1.f, 0.f, 0.f, 0.f);
            __syncthreads();

            // ---- X B-frags (hi/lo): B[k=quad*8+j][n=l16] = X[n][k], k>=16 -> 0 ----
            const int kq = (quad < 2) ? quad : 1;
            const float4 xa = *(const float4*)(wb + oX + l16 * 80 + kq * 32);
            const float4 xb = *(const float4*)(wb + oX + l16 * 80 + kq * 32 + 16);
            float xv[8] = {xa.x, xa.y, xa.z, xa.w, xb.x, xb.y, xb.z, xb.w};
            bf16x8 xhi, xlo;
            #pragma unroll
            for (int j = 0; j < 8; ++j) {
                const float f = (quad < 2) ? xv[j] : 0.f;
                const unsigned short hb = rne_bf16(f);
                xhi[j] = (short)hb;
                xlo[j] = (short)rne_bf16(f - bf16f(hb));
            }

            // ---- L1: D = W1·X^T (3-term), ELU, pack 4 rows -> H1[samp][feat] ----
            #pragma unroll
            for (int mt = 0; mt < 8; ++mt) {
                f32x4 acc = {0.f, 0.f, 0.f, 0.f};
                acc = MFMA(w1hi[mt], xhi, acc);
                acc = MFMA(w1hi[mt], xlo, acc);
                acc = MFMA(w1lo[mt], xhi, acc);
                bf16x4 pk;
                #pragma unroll
                for (int r = 0; r < 4; ++r) pk[r] = (short)rne_bf16(elu_f(acc[r]));
                *(bf16x4*)(wb + oH1 + l16 * 272 + mt * 32 + quad * 8) = pk;
            }
            __syncthreads();

            // ---- L2: D = W2·H1^T, bias, ELU -> H2[samp][feat] ----
            const bf16x8 hb0 = *(const bf16x8*)(wb + oH1 + l16 * 272 +   0 + quad * 16);
            const bf16x8 hb1 = *(const bf16x8*)(wb + oH1 + l16 * 272 +  64 + quad * 16);
            const bf16x8 hb2 = *(const bf16x8*)(wb + oH1 + l16 * 272 + 128 + quad * 16);
            const bf16x8 hb3 = *(const bf16x8*)(wb + oH1 + l16 * 272 + 192 + quad * 16);
            #pragma unroll
            for (int mt = 0; mt < 2; ++mt) {
                f32x4 acc = {0.f, 0.f, 0.f, 0.f};
                acc = MFMA(w2f[mt][0], hb0, acc);
                acc = MFMA(w2f[mt][1], hb1, acc);
                acc = MFMA(w2f[mt][2], hb2, acc);
                acc = MFMA(w2f[mt][3], hb3, acc);
                bf16x4 pk;
                #pragma unroll
                for (int r = 0; r < 4; ++r)
                    pk[r] = (short)rne_bf16(elu_f(acc[r] + b2r[mt][r]));
                *(bf16x4*)(wb + oX /*==H2*/ + l16 * 80 + mt * 32 + quad * 8) = pk;
            }
            __syncthreads();

            // ---- L3: D = W3·H2^T, bias, softplus -> L[samp][t] (f32) ----
            const bf16x8 h2b = *(const bf16x8*)(wb + oX + l16 * 80 + quad * 16);
            #pragma unroll
            for (int mt = 0; mt < 5; ++mt) {
                const f32x4 z = {0.f, 0.f, 0.f, 0.f};
                const f32x4 acc = MFMA(w3f[mt], h2b, z);
                float4 lv;
                lv.x = softplus_f(acc[0] + b3r[mt][0]);
                lv.y = softplus_f(acc[1] + b3r[mt][1]);
                lv.z = softplus_f(acc[2] + b3r[mt][2]);
                lv.w = softplus_f(acc[3] + b3r[mt][3]);
                *(float4*)(wb + oL + (nt * 16 + l16) * 336 + mt * 64 + quad * 16) = lv;
            }
            __syncthreads();
        }

        // ---- L·L^T (lane-per-sample) + row-batched coalesced store ----
        float Lr[80];
        if (lane < 32) {
            #pragma unroll
            for (int u2 = 0; u2 < 20; ++u2) {
                const float4 v4 = *(const float4*)(wb + oL + lane * 336 + u2 * 16);
                Lr[4*u2+0] = v4.x; Lr[4*u2+1] = v4.y; Lr[4*u2+2] = v4.z; Lr[4*u2+3] = v4.w;
            }
        }
        float* og = out + (size_t)base32 * 144;
        #pragma unroll
        for (int b = 0; b < 3; ++b) {
            if (lane < 32) {
                #pragma unroll
                for (int i4 = 0; i4 < 4; ++i4) {
                    const int i = 4 * b + i4;
                    #pragma unroll
                    for (int k0 = 0; k0 < 12; k0 += 4) {
                        float r4[4];
                        #pragma unroll
                        for (int kk = 0; kk < 4; ++kk) {
                            const int k = k0 + kk;
                            const int m = (i < k) ? i : k;
                            float s0 = 0.f, s1 = 0.f;
                            #pragma unroll
                            for (int j = 0; j <= m; ++j) {
                                const float p = Lr[i*(i+1)/2 + j] * Lr[k*(k+1)/2 + j];
                                if (j & 1) s1 += p; else s0 += p;
                            }
                            r4[kk] = s0 + s1;
                        }
                        *(float4*)(wb + oL /*staging*/ + lane * 208 + (i4 * 12 + k0) * 4) =
                            make_float4(r4[0], r4[1], r4[2], r4[3]);
                    }
                }
            }
            __syncthreads();
            // 32 samples x 4 rows = 384 float4; runs of 192 B = 3 full lines each
            #pragma unroll
            for (int p = 0; p < 6; ++p) {
                const int u = p * 64 + lane;
                const int samp = u / 12, q = u - samp * 12;
                const float4 v4 = *(const float4*)(wb + oL + samp * 208 + q * 16);
                *(float4*)(og + samp * 144 + b * 48 + q * 4) = v4;
            }
            __syncthreads();
        }
    }
}

} // namespace

extern "C" void kernel_launch(void* const* d_in, const int* in_sizes, int n_in,
                              void* d_out, int out_size, void* d_ws, size_t ws_size,
                              hipStream_t stream) {
    const float* x  = (const float*)d_in[0];
    const float* W1 = (const float*)d_in[1];
    const float* b1 = (const float*)d_in[2];
    const float* W2 = (const float*)d_in[3];
    const float* b2 = (const float*)d_in[4];
    const float* W3 = (const float*)d_in[5];
    const float* b3 = (const float*)d_in[6];
    float* out = (float*)d_out;

    const int batch  = in_sizes[0] / 12;   // 262144
    const int blocks = batch / 512;        // 512 blocks x 4 waves x 128 samples

    qnc_mfma<<<blocks, 256, 0, stream>>>(x, W1, b1, W2, b2, W3, b3, out);
}